// Round 12
// baseline (89.958 us; speedup 1.0000x reference)
//
#include <hip/hip_runtime.h>
#include <stdint.h>

// Problem constants (B,C,H,W)=(4,128,64,128), R=4, D=9, out channels 81.
// out[b, di*9+dj, h, w] = sum_c src[b,c,h,w] * tgt[b,c,h+di-8,w+dj-8]
// (zero when the shifted index leaves [0,H)x[0,W); shifts are [-8,0]).
//
// v13 = v10's converter + fragment-direct main kernel with v11's h-span
// blocking. R11 accounting: v12's kernel (~31us) = ~15us memory service
// + ~16us ring-prologue latency (9 slices staged serially before any
// MFMA at 9 waves/CU). Fix: pre-converted bf16 K-panel planes in d_ws
// mean the main kernel needs NO input LDS / f2bf / ds_write at all —
// fragments are single 16B global loads (v9-verified). Block =
// (b, h-span 4, w-quarter): A planes from L1 across waves, 12 unique
// tgt rows per block, ~41 MB far + 50 MB converter, fully streamed.
#define NB 4
#define NC 128
#define NH 64
#define NW 128
#define HW (NH * NW)      // 8192
#define ND 9
#define NOUT (ND * ND)    // 81
#define SH 4              // h rows per block
#define QW 32             // w-quarter width
#define PLANE 16384       // halfwords per (b,row) bf16 K-panel plane (32 KB)
#define TGT_OFF ((size_t)NB * NH * PLANE)  // tgt planes after src planes
#define OTILE (ND * 32)   // floats per di slice of outlds

typedef __attribute__((ext_vector_type(8))) short short8;
typedef __attribute__((ext_vector_type(4))) float f32x4;

__device__ __forceinline__ ushort f2bf(float f) {  // RNE f32->bf16
  uint u = __float_as_uint(f);
  u += 0x7FFFu + ((u >> 16) & 1u);
  return (ushort)(u >> 16);
}

// ---- pass 1 (v10 verbatim, refcheck'd 3x): f32 -> bf16 K-panel planes.
// plane(b,row)[oct=c>>3][w][c&7]; LDS-transposed so reads and writes are
// both coalesced.
__global__ __launch_bounds__(512, 2) void convert_kernel(const float* __restrict__ src,
                                                         const float* __restrict__ tgt,
                                                         ushort* __restrict__ ws) {
  __shared__ ushort pl[PLANE];
  const int xcd = blockIdx.x & 7;
  const int j   = blockIdx.x >> 3;        // 0..63
  const int b   = xcd >> 1;
  const int t   = j >> 5;                 // 0 = src, 1 = tgt
  const int row = ((xcd & 1) << 5) | (j & 31);
  const float* in = (t ? tgt : src) + (size_t)(b * NC) * HW + row * NW;
  ushort* outp = ws + (t ? TGT_OFF : 0) + (size_t)(b * NH + row) * PLANE;

#pragma unroll
  for (int i = 0; i < 8; ++i) {
    const int cell = i * 512 + threadIdx.x;  // 4096 cells = 32 c-quads x 128 w
    const int c0 = (cell >> 7) << 2;         // 0,4,...,124
    const int w  = cell & 127;
    ushort4 e;
    e.x = f2bf(in[(size_t)(c0 + 0) * HW + w]);
    e.y = f2bf(in[(size_t)(c0 + 1) * HW + w]);
    e.z = f2bf(in[(size_t)(c0 + 2) * HW + w]);
    e.w = f2bf(in[(size_t)(c0 + 3) * HW + w]);
    *(ushort4*)&pl[(c0 >> 3) * 1024 + w * 8 + (c0 & 7)] = e;
  }
  __syncthreads();
#pragma unroll
  for (int i = 0; i < 4; ++i) {
    const int idx = i * 512 + threadIdx.x;   // 2048 x 16B, linear
    *(uint4*)(outp + idx * 8) = *(const uint4*)&pl[idx * 8];
  }
}

// ---- pass 2: fragment-direct banded Gram. Block=(b, h-span 4, quarter);
// 9 waves, wave = di. Per h: wave loads A0/A1 (m-tiles at w0, w0+16) and
// B tiles at n0 = w0-16 (q>0), w0, w0+16 — all single 16B loads from the
// K-panel planes — then 12-16 MFMA, band-extract to outlds, store.
__global__ __launch_bounds__(576, 1) void costvol_kernel(const ushort* __restrict__ ws,
                                                         float* __restrict__ out) {
  __shared__ float outlds[ND * OTILE];    // 10.4 KB: 9 di slices x 9dj x 32w
  const int tid  = threadIdx.x;
  const int lane = tid & 63;
  const int wave = tid >> 6;              // 0..8 == di
  const int col  = lane & 15;
  const int g    = lane >> 4;

  // decode (v12's): 256 blocks = 8 xcd * 32; combo=(b*4+q) pinned mod 8.
  const int xcd   = blockIdx.x & 7;
  const int r     = blockIdx.x >> 3;      // 0..31
  const int combo = ((r >> 4) << 3) | xcd;
  const int b     = combo >> 2;
  const int q     = combo & 3;
  const int h0    = (r & 15) << 2;
  const int w0    = q * QW;

  const ushort* apl = ws + (size_t)(b * NH) * PLANE;            // src planes
  const ushort* tpl = ws + TGT_OFF + (size_t)(b * NH) * PLANE;  // tgt planes

  for (int hh = 0; hh < SH; ++hh) {
    const int h = h0 + hh;
    const int y = h + wave - 8;           // this wave's tgt row (di = wave)

    if (y >= 0) {
      const ushort* ap = apl + (size_t)h * PLANE;
      const ushort* tp = tpl + (size_t)y * PLANE;

      short8 A0[4], A1[4], B0[4], Bp[4], Bm[4];
#pragma unroll
      for (int kk = 0; kk < 4; ++kk) {
        const int ro = (4 * kk + g) * 1024;
        A0[kk] = *(const short8*)&ap[ro + (w0 + col) * 8];
        A1[kk] = *(const short8*)&ap[ro + (w0 + 16 + col) * 8];
        B0[kk] = *(const short8*)&tp[ro + (w0 + col) * 8];
        Bp[kk] = *(const short8*)&tp[ro + (w0 + 16 + col) * 8];
      }
      if (q) {
#pragma unroll
        for (int kk = 0; kk < 4; ++kk)
          Bm[kk] = *(const short8*)&tp[(4 * kk + g) * 1024 + (w0 - 16 + col) * 8];
      }

      f32x4 aD0 = {0.f,0.f,0.f,0.f}, aS0 = {0.f,0.f,0.f,0.f};
      f32x4 aD1 = {0.f,0.f,0.f,0.f}, aS1 = {0.f,0.f,0.f,0.f};
#pragma unroll
      for (int kk = 0; kk < 4; ++kk) {
        aD0 = __builtin_amdgcn_mfma_f32_16x16x32_bf16(A0[kk], B0[kk], aD0, 0, 0, 0);
        aS1 = __builtin_amdgcn_mfma_f32_16x16x32_bf16(A1[kk], B0[kk], aS1, 0, 0, 0);
        aD1 = __builtin_amdgcn_mfma_f32_16x16x32_bf16(A1[kk], Bp[kk], aD1, 0, 0, 0);
      }
      if (q) {
#pragma unroll
        for (int kk = 0; kk < 4; ++kk)
          aS0 = __builtin_amdgcn_mfma_f32_16x16x32_bf16(A0[kk], Bm[kk], aS0, 0, 0, 0);
      }
      // q==0: aS0 stays zero; its extraction slots are all under the
      // w+dj<8 wedge mask, so writing zeros there is harmless.

      // band extraction (v9/v12-verified): C/D layout col=lane&15, row=4g+qr.
      // diag: dj=col-row+8 (row+dj>=8); sub: dj=col-row-8 (row+dj<=7) —
      // exact partition. Swizzle (wl+4*dj)&31 spreads the dj-stride.
      float* ol = &outlds[wave * OTILE];
#pragma unroll
      for (int qr = 0; qr < 4; ++qr) {
        const int row = 4 * g + qr;
        const int djd = col - row + 8;
        const int djs = col - row - 8;
        if (djd >= 0 && djd <= 8) {
          ol[djd * 32 + ((row + 4 * djd) & 31)]      = aD0[qr];
          ol[djd * 32 + ((16 + row + 4 * djd) & 31)] = aD1[qr];
        }
        if (djs >= 0 && djs <= 8) {
          ol[djs * 32 + ((row + 4 * djs) & 31)]      = aS0[qr];
          ol[djs * 32 + ((16 + row + 4 * djs) & 31)] = aS1[qr];
        }
      }
    }
    __syncthreads();                      // scatter done

    // store this h (9 di x 9 dj x 32 w, float4). Zeros for y<0 planes and
    // the w+dj<8 wedge (stale/garbage LDS never leaks through the masks).
    for (int s = tid; s < ND * ND * 8; s += 576) {
      const int di = s / 72;
      const int rr = s % 72;
      const int dj = rr >> 3;
      const int w4 = (rr & 7) << 2;
      f32x4 o = *(const f32x4*)&outlds[di * OTILE + dj * 32 + ((w4 + 4 * dj) & 31)];
      const bool vb = (h + di - 8) >= 0;
      const int wg = w0 + w4;
#pragma unroll
      for (int i = 0; i < 4; ++i)
        if (!vb || (wg + i + dj < 8)) o[i] = 0.f;
      *(f32x4*)(out + ((size_t)((b * NOUT + di * ND + dj) * NH + h)) * NW + wg) = o;
    }
    __syncthreads();                      // outlds readers done before next h
  }
}

extern "C" void kernel_launch(void* const* d_in, const int* in_sizes, int n_in,
                              void* d_out, int out_size, void* d_ws, size_t ws_size,
                              hipStream_t stream) {
  const float* src = (const float*)d_in[0];
  const float* tgt = (const float*)d_in[1];
  float* out = (float*)d_out;
  ushort* ws = (ushort*)d_ws;
  convert_kernel<<<dim3(2 * NB * NH), dim3(512), 0, stream>>>(src, tgt, ws);
  costvol_kernel<<<dim3(NB * NH), dim3(576), 0, stream>>>(ws, out);
}

// Round 13
// 87.008 us; speedup vs baseline: 1.0339x; 1.0339x over previous
//
#include <hip/hip_runtime.h>
#include <stdint.h>

// Problem constants (B,C,H,W)=(4,128,64,128), R=4, D=9, out channels 81.
// out[b, di*9+dj, h, w] = sum_c src[b,c,h,w] * tgt[b,c,h+di-8,w+dj-8]
// (zero when the shifted index leaves [0,H)x[0,W); shifts are [-8,0]).
//
// v14 = v12 (best, 86.1us) with the h-span stretched: SH 4->8, Wp 32->16
// (same 256 blocks = 1/CU). R12 accounting: 80% of v12's far reads were
// in the serial 9-slice ring prologue with only 3 slides to amortize it;
// two-pass variants (v8/v9/v10/v13) all pay an extra dispatch gap and
// land ~90. v14 keeps the verified single-kernel ring structure: volume
// 92->82 MB, prologue fraction 80->45% (9 slices / 7 slides), LDS 116 KB.
// Staging (b128 writes), T14 issue-early slide, band extraction and
// wedge-masked store reuse v12's refcheck'd formulas at Wp=16.
#define NB 4
#define NC 128
#define NH 64
#define NW 128
#define HW (NH * NW)      // 8192
#define ND 9
#define NOUT (ND * ND)    // 81
#define SH 8              // h rows per block
#define QW 16             // w-part width
#define TROW 264          // halfwords per oct-row, tgt slice ((16+16)*8 + 8 pad)
#define SROW 136          // halfwords per oct-row, src slice (16*8 + 8 pad)
#define OTILE (ND * 16)   // floats per di slice of outlds (144)

typedef __attribute__((ext_vector_type(8))) short short8;
typedef __attribute__((ext_vector_type(4))) float f32x4;

__device__ __forceinline__ ushort f2bf(float f) {  // RNE f32->bf16
  uint u = __float_as_uint(f);
  u += 0x7FFFu + ((u >> 16) & 1u);
  return (ushort)(u >> 16);
}

__global__ __launch_bounds__(576, 1) void costvol_kernel(const float* __restrict__ src,
                                                         const float* __restrict__ tgt,
                                                         float* __restrict__ out) {
  __shared__ ushort tgtS[9][16 * TROW];   // 76.0 KB ring of tgt slices
  __shared__ ushort srcS[SH][16 * SROW];  // 34.8 KB src slices
  __shared__ float  outlds[ND * OTILE];   // 5.2 KB band tile (per h)

  const int tid  = threadIdx.x;
  const int lane = tid & 63;
  const int wave = tid >> 6;              // 0..8 == di
  const int col  = lane & 15;
  const int g    = lane >> 4;

  // decode: 256 blocks = 8 xcd * 32. xcd owns (b, h-half); within an xcd
  // k = (h0sub<<3)|q so the 8 q-parts of one h-span launch adjacently.
  const int xcd = blockIdx.x & 7;
  const int k   = blockIdx.x >> 3;        // 0..31
  const int b   = xcd >> 1;
  const int q   = k & 7;
  const int h0  = ((xcd & 1) << 5) | ((k >> 3) << 3);
  const int w0  = q * QW;

  const float* sb = src + (size_t)(b * NC) * HW;
  const float* tb = tgt + (size_t)(b * NC) * HW;

  // ---- prologue: src slices. cell = (hh, oct o, col-quad fc): 8 coalesced
  // float4 loads (c = 8o..8o+7), pack, 4 ds_write_b128.
  for (int cell = tid; cell < SH * 64; cell += 576) {
    const int hh = cell >> 6;
    const int cc = cell & 63;
    const int o  = cc >> 2;
    const int fc = cc & 3;
    const float* p = sb + (size_t)(h0 + hh) * NW + w0 + 4 * fc + (size_t)(o * 8) * HW;
    float4 v[8];
#pragma unroll
    for (int j = 0; j < 8; ++j) v[j] = *(const float4*)(p + (size_t)j * HW);
    ushort* d = srcS[hh] + o * SROW + (4 * fc) * 8;
#pragma unroll
    for (int i = 0; i < 4; ++i) {
      short8 e;
#pragma unroll
      for (int j = 0; j < 8; ++j) e[j] = (short)f2bf(((const float*)&v[j])[i]);
      *(short8*)&d[i * 8] = e;
    }
  }
  // ---- prologue: initial tgt window, rows y0..h0 (<=9 slices x 128 cells).
  // Left halo cols <0 clamped (finite garbage, consumed only under the
  // wedge mask in the store pass).
  {
    const int y0  = (h0 >= 8) ? h0 - 8 : 0;
    const int nts = h0 - y0 + 1;
    for (int cell = tid; cell < nts * 128; cell += 576) {
      const int y  = y0 + (cell >> 7);
      const int cc = cell & 127;
      const int o  = cc >> 3;
      const int fc = cc & 7;
      const int g0 = w0 - 16 + 4 * fc;           // quad all-in or all-out
      const float* p = tb + (size_t)y * NW + (g0 < 0 ? 0 : g0) + (size_t)(o * 8) * HW;
      float4 v[8];
#pragma unroll
      for (int j = 0; j < 8; ++j) v[j] = *(const float4*)(p + (size_t)j * HW);
      ushort* d = tgtS[y % 9] + o * TROW + (4 * fc) * 8;
#pragma unroll
      for (int i = 0; i < 4; ++i) {
        short8 e;
#pragma unroll
        for (int j = 0; j < 8; ++j) e[j] = (short)f2bf(((const float*)&v[j])[i]);
        *(short8*)&d[i * 8] = e;
      }
    }
  }
  __syncthreads();

  for (int hh = 0; hh < SH; ++hh) {
    const int h = h0 + hh;

    // T14 issue-early: next tgt slice (128 cells, waves 0-1 — the waves
    // most often y<0-idle) loaded BEFORE the MFMA phase; ds_write after
    // the scatter barrier (slot (h+1)%9 holds y=h-8, read this h).
    float4 pv[8];
    const bool hs = (hh < SH - 1) && (tid < 128);
    int so = 0, sfc = 0;
    if (hs) {
      so  = tid >> 3;
      sfc = tid & 7;
      const int g0 = w0 - 16 + 4 * sfc;
      const float* p = tb + (size_t)(h + 1) * NW + (g0 < 0 ? 0 : g0) + (size_t)(so * 8) * HW;
#pragma unroll
      for (int j = 0; j < 8; ++j) pv[j] = *(const float4*)(p + (size_t)j * HW);
    }

    const int y = h + wave - 8;           // this wave's tgt row (di = wave)
    if (y >= 0) {
      const ushort* Bp = tgtS[y % 9];
      const ushort* Ap = srcS[hh];
      // A tile: local cols 0..15 = global w0..w0+15. B tiles: local 16
      // (diag, n0=w0) and local 0 (sub, n0=w0-16; skipped for q=0 — its
      // band slots are entirely under the wedge mask).
      short8 A[4], BD[4];
#pragma unroll
      for (int kk = 0; kk < 4; ++kk) {
        const int ro = 4 * kk + g;
        A[kk]  = *(const short8*)&Ap[ro * SROW + col * 8];
        BD[kk] = *(const short8*)&Bp[ro * TROW + (16 + col) * 8];
      }
      f32x4 aD = {0.f, 0.f, 0.f, 0.f};
      f32x4 aS = {0.f, 0.f, 0.f, 0.f};
#pragma unroll
      for (int kk = 0; kk < 4; ++kk)
        aD = __builtin_amdgcn_mfma_f32_16x16x32_bf16(A[kk], BD[kk], aD, 0, 0, 0);
      if (q) {
#pragma unroll
        for (int kk = 0; kk < 4; ++kk) {
          const short8 BS = *(const short8*)&Bp[(4 * kk + g) * TROW + col * 8];
          aS = __builtin_amdgcn_mfma_f32_16x16x32_bf16(A[kk], BS, aS, 0, 0, 0);
        }
      }

      // band extraction (v9/v12-verified): C/D layout col=lane&15, row=4g+qr.
      // diag: dj=col-row+8 (row+dj>=8); sub: dj=col-row-8 (row+dj<=7) —
      // exact partition. Swizzle (w+4*dj)&15 spreads the dj-stride.
      float* ol = &outlds[wave * OTILE];
#pragma unroll
      for (int qr = 0; qr < 4; ++qr) {
        const int row = 4 * g + qr;
        const int djd = col - row + 8;
        const int djs = col - row - 8;
        if (djd >= 0 && djd <= 8) ol[djd * 16 + ((row + 4 * djd) & 15)] = aD[qr];
        if (djs >= 0 && djs <= 8) ol[djs * 16 + ((row + 4 * djs) & 15)] = aS[qr];
      }
    }
    __syncthreads();                      // scatter done

    // store this h (9 di x 9 dj x 16 w, float4 = 324 stores). Zeros for
    // y<0 planes and the w+dj<8 wedge (stale LDS never leaks through).
    for (int s = tid; s < ND * ND * 4; s += 576) {
      const int di = s / 36;
      const int rr = s % 36;
      const int dj = rr >> 2;
      const int w4 = (rr & 3) << 2;
      f32x4 o = *(const f32x4*)&outlds[di * OTILE + dj * 16 + ((w4 + 4 * dj) & 15)];
      const bool vb = (h + di - 8) >= 0;
      const int wg = w0 + w4;
#pragma unroll
      for (int i = 0; i < 4; ++i)
        if (!vb || (wg + i + dj < 8)) o[i] = 0.f;
      *(f32x4*)(out + ((size_t)((b * NOUT + di * ND + dj) * NH + h)) * NW + wg) = o;
    }

    // T14 write-late: land the pre-loaded slice into the freed ring slot.
    if (hs) {
      ushort* d = tgtS[(h + 1) % 9] + so * TROW + (4 * sfc) * 8;
#pragma unroll
      for (int i = 0; i < 4; ++i) {
        short8 e;
#pragma unroll
        for (int j = 0; j < 8; ++j) e[j] = (short)f2bf(((const float*)&pv[j])[i]);
        *(short8*)&d[i * 8] = e;
      }
    }
    __syncthreads();                      // outlds read + new slice ready
  }
}

extern "C" void kernel_launch(void* const* d_in, const int* in_sizes, int n_in,
                              void* d_out, int out_size, void* d_ws, size_t ws_size,
                              hipStream_t stream) {
  const float* src = (const float*)d_in[0];
  const float* tgt = (const float*)d_in[1];
  float* out = (float*)d_out;
  costvol_kernel<<<dim3(256), dim3(576), 0, stream>>>(src, tgt, out);
}